// Round 6
// baseline (84.698 us; speedup 1.0000x reference)
//
#include <hip/hip_runtime.h>

#define NN 2048
#define AD 64
#define HH 8
#define DD 512
#define NEG 0.2f

typedef float f32x4 __attribute__((ext_vector_type(4)));
typedef _Float16 half8 __attribute__((ext_vector_type(8)));
typedef _Float16 half2v __attribute__((ext_vector_type(2)));
typedef unsigned short u16;
typedef u16 u16x8 __attribute__((ext_vector_type(8)));

// ---------------------------------------------------------------------------
// Kernel 1: Q = X@Qw + Qb, K = X@Kw + Kb, VtH = f16(X@Vw + Vb)^T  (unchanged)
// ---------------------------------------------------------------------------
__global__ __launch_bounds__(256) void qkv_kernel(
    const float* __restrict__ X,
    const float* __restrict__ Qw, const float* __restrict__ Qb,
    const float* __restrict__ Kw, const float* __restrict__ Kb,
    const float* __restrict__ Vw, const float* __restrict__ Vb,
    float* __restrict__ Q, float* __restrict__ K, u16* __restrict__ VtH) {
  __shared__ float Xs[64][68];
  int t = threadIdx.x;
  int b = blockIdx.x;
  int m = b >> 7;           // 0:Q 1:K 2:V
  int tile = b & 127;
  int r0 = (tile >> 2) * 64;
  int d0 = (tile & 3) * 128;
  const float* W  = (m == 0) ? Qw : (m == 1) ? Kw : Vw;
  const float* Bv = (m == 0) ? Qb : (m == 1) ? Kb : Vb;

  for (int idx = t; idx < 64 * 64; idx += 256) {
    int r = idx >> 6, c = idx & 63;
    Xs[r][c] = X[(size_t)(r0 + r) * AD + c];
  }
  __syncthreads();

  int tr = t >> 5;
  int td = t & 31;
  int d = d0 + td * 4;
  float4 bias = *(const float4*)&Bv[d];
  float4 acc[8];
#pragma unroll
  for (int i = 0; i < 8; ++i) acc[i] = bias;
  for (int c = 0; c < 64; ++c) {
    float4 w = *(const float4*)&W[c * DD + d];
#pragma unroll
    for (int i = 0; i < 8; ++i) {
      float x = Xs[tr * 8 + i][c];
      acc[i].x += x * w.x; acc[i].y += x * w.y;
      acc[i].z += x * w.z; acc[i].w += x * w.w;
    }
  }
  if (m == 2) {
#pragma unroll
    for (int c = 0; c < 4; ++c) {
      u16x8 o;
#pragma unroll
      for (int i = 0; i < 8; ++i) {
        float fv = (c == 0) ? acc[i].x : (c == 1) ? acc[i].y
                 : (c == 2) ? acc[i].z : acc[i].w;
        _Float16 hf = (_Float16)fv;
        o[i] = __builtin_bit_cast(u16, hf);
      }
      *(u16x8*)&VtH[(size_t)(d + c) * NN + r0 + tr * 8] = o;
    }
  } else {
    float* O = (m == 0) ? Q : K;
#pragma unroll
    for (int i = 0; i < 8; ++i) {
      *(float4*)&O[(size_t)(r0 + tr * 8 + i) * DD + d] = acc[i];
    }
  }
}

// ---------------------------------------------------------------------------
// Kernel 2: S-scores -> f16 product tables.
// TS[row][kk][0..7] = f16(exp(S)*0.25) (pos), [kk][8..15] = f16(exp(0.2S)*0.25)
// with kk = k ^ (row&7)  (XOR bank swizzle). grid 512 (4 rows), block 256.
// leaky+exp are replaced downstream by max(pos_i*pos_j, neg_i*neg_j).
// ---------------------------------------------------------------------------
__global__ __launch_bounds__(256) void s12_kernel(
    const float* __restrict__ Q, const float* __restrict__ K,
    const float* __restrict__ A,
    u16* __restrict__ TS1, u16* __restrict__ TS2) {
  __shared__ float Qs[4][512];
  __shared__ float Ks[4][512];
  __shared__ float red1[4][4][64];
  __shared__ float red2[4][4][64];
  int t = threadIdx.x;
  int r0 = blockIdx.x * 4;
  for (int idx = t; idx < 4 * 128; idx += 256) {
    int r = idx >> 7, dd = (idx & 127) * 4;
    *(float4*)&Qs[r][dd] = *(const float4*)&Q[(size_t)(r0 + r) * DD + dd];
    *(float4*)&Ks[r][dd] = *(const float4*)&K[(size_t)(r0 + r) * DD + dd];
  }
  __syncthreads();
  int kh = t & 63;
  int dg = t >> 6;
  int k = kh >> 3, h = kh & 7;
  float as1[4], as2[4];
#pragma unroll
  for (int i = 0; i < 4; ++i) { as1[i] = 0.f; as2[i] = 0.f; }
  const float* A1 = A + (size_t)k * 1024 * 8 + h;
  const float* A2 = A1 + 512 * 8;
  for (int dq = 0; dq < 32; ++dq) {
    int dd = dg * 128 + dq * 4;
    float a10 = A1[(dd + 0) * 8], a11 = A1[(dd + 1) * 8],
          a12 = A1[(dd + 2) * 8], a13 = A1[(dd + 3) * 8];
    float a20 = A2[(dd + 0) * 8], a21 = A2[(dd + 1) * 8],
          a22 = A2[(dd + 2) * 8], a23 = A2[(dd + 3) * 8];
#pragma unroll
    for (int i = 0; i < 4; ++i) {
      float4 q  = *(const float4*)&Qs[i][dd];
      float4 kk = *(const float4*)&Ks[i][dd];
      as1[i] += q.x  * a10 + q.y  * a11 + q.z  * a12 + q.w  * a13;
      as2[i] += kk.x * a20 + kk.y * a21 + kk.z * a22 + kk.w * a23;
    }
  }
#pragma unroll
  for (int i = 0; i < 4; ++i) {
    red1[dg][i][kh] = as1[i];
    red2[dg][i][kh] = as2[i];
  }
  __syncthreads();
  {
    int i = t >> 6, kk2 = t & 63;
    float v1 = red1[0][i][kk2] + red1[1][i][kk2] + red1[2][i][kk2] + red1[3][i][kk2];
    float v2 = red2[0][i][kk2] + red2[1][i][kk2] + red2[2][i][kk2] + red2[3][i][kk2];
    int kq = kk2 >> 3, h = kk2 & 7;
    int row = r0 + i;
    int kki = (kq ^ (row & 7)) << 4;
    u16* T1 = TS1 + (size_t)row * 128 + kki;
    u16* T2 = TS2 + (size_t)row * 128 + kki;
    _Float16 p1 = (_Float16)(__expf(v1) * 0.25f);
    _Float16 n1 = (_Float16)(__expf(NEG * v1) * 0.25f);
    _Float16 p2 = (_Float16)(__expf(v2) * 0.25f);
    _Float16 n2 = (_Float16)(__expf(NEG * v2) * 0.25f);
    T1[h]     = __builtin_bit_cast(u16, p1);
    T1[8 + h] = __builtin_bit_cast(u16, n1);
    T2[h]     = __builtin_bit_cast(u16, p2);
    T2[8 + h] = __builtin_bit_cast(u16, n2);
  }
}

// ---------------------------------------------------------------------------
// Kernel 3: MFMA attention, product-table scoring (no exp in the hot loop).
// grid 512 = 128 i-tiles (16 rows) x 4 j-chunks (512 j). block 512 = 8 waves.
// Per 64-j tile, 1 barrier:
//  Phase A: thread (i_loc = w*2 + lane>>5; j = 2m, 2m+1):
//    k = clip(E); p8 = max(pos_i*pos_j, neg_i*neg_j) via v_pk_mul/max_f16
//    (invalid -> 1/16); h-pairs written to PA[h][i][j].
//  Phase B (wave = head w): afrag = b128 from PA; bfrag from VtH (issued
//    pre-phase-A); 8 MFMAs numerator + 2 ones-MFMAs -> exact f32 denominator
//    from the SAME f16 p (num/denom consistent).
//  s2-table staging: loads issued at tile top, LDS-written post-phase-A (T14).
// ---------------------------------------------------------------------------
__global__ __launch_bounds__(512, 4) void attn_mfma_kernel(
    const int* __restrict__ E,
    const u16* __restrict__ TS1, const u16* __restrict__ TS2,
    const u16* __restrict__ VtH,
    float* __restrict__ PART, float* __restrict__ LPART) {
  __shared__ _Float16 s1t[16 * 128];        // 4 KB  [i][kk*16+{8pos,8neg}]
  __shared__ _Float16 s2t[2][64 * 128];     // 32 KB [j][kk*16+{8pos,8neg}]
  __shared__ _Float16 PA[2][8][16][72];     // 36.9 KB [h][i][j]
  int t = threadIdx.x;
  int w = t >> 6, lane = t & 63;
  int li = lane & 15, q = lane >> 4;
  int m = lane & 31;
  int i_loc = w * 2 + (lane >> 5);
  int it = blockIdx.x >> 2, ch = blockIdx.x & 3;
  int i0 = it * 16, jch = ch * 512;

  const half8 SIX8 = {(_Float16)0.0625f, (_Float16)0.0625f, (_Float16)0.0625f,
                      (_Float16)0.0625f, (_Float16)0.0625f, (_Float16)0.0625f,
                      (_Float16)0.0625f, (_Float16)0.0625f};
  const half8 ONE8 = {(_Float16)1.0f, (_Float16)1.0f, (_Float16)1.0f,
                      (_Float16)1.0f, (_Float16)1.0f, (_Float16)1.0f,
                      (_Float16)1.0f, (_Float16)1.0f};

  // stage s1t (16 rows x 256B)
  if (t < 256) {
    *(u16x8*)&s1t[t * 8] = *(const u16x8*)&TS1[(size_t)i0 * 128 + t * 8];
  }
  // stage tile 0 s2 tables directly
  {
    const u16* src = TS2 + (size_t)jch * 128;
    *(u16x8*)&s2t[0][t * 8]        = *(const u16x8*)&src[t * 8];
    *(u16x8*)&s2t[0][4096 + t * 8] = *(const u16x8*)&src[4096 + t * 8];
  }
  const int* Erow = E + (size_t)(i0 + i_loc) * NN;
  int2 eCur = *(const int2*)(Erow + jch + 2 * m);
  __syncthreads();

  f32x4 acc[4];
#pragma unroll
  for (int n = 0; n < 4; ++n) acc[n] = (f32x4){0.f, 0.f, 0.f, 0.f};
  f32x4 acc_l = (f32x4){0.f, 0.f, 0.f, 0.f};
  int cur = 0;

#pragma unroll 1
  for (int jt = 0; jt < 8; ++jt) {
    int jb = jch + jt * 64;

    // issue next tile's staging loads + E prefetch (written to LDS later)
    u16x8 stA, stB;
    int2 eNxt = eCur;
    if (jt < 7) {
      const u16* src = TS2 + (size_t)(jb + 64) * 128;
      stA = *(const u16x8*)&src[t * 8];
      stB = *(const u16x8*)&src[4096 + t * 8];
      eNxt = *(const int2*)(Erow + jb + 64 + 2 * m);
    }

    // bfrag loads for THIS tile (consumed after barrier; drained there)
    half8 bfrag[4][2];
#pragma unroll
    for (int n = 0; n < 4; ++n)
#pragma unroll
      for (int s = 0; s < 2; ++s) {
        const u16* p = &VtH[(size_t)(w * 64 + n * 16 + li) * NN + jb + s * 32 + q * 8];
        bfrag[n][s] = *(const half8*)p;
      }

    // ---- Phase A: p = max(pos_i*pos_j, neg_i*neg_j), 8 heads packed
    const _Float16* s1row = &s1t[i_loc * 128];
    const _Float16* s2row = &s2t[cur][0];
    half8 pmj[2];
#pragma unroll
    for (int jj = 0; jj < 2; ++jj) {
      int ev = jj ? eCur.y : eCur.x;
      int j = 2 * m + jj;
      int k = min(max(ev, 0), 7);
      int kki = (k ^ (i_loc & 7)) << 4;
      int kkj = (k ^ (j & 7)) << 4;
      half8 ip = *(const half8*)&s1row[kki];
      half8 in_ = *(const half8*)&s1row[kki + 8];
      half8 jp = *(const half8*)&s2row[j * 128 + kkj];
      half8 jn = *(const half8*)&s2row[j * 128 + kkj + 8];
      half8 pp = ip * jp;
      half8 pn = in_ * jn;
      half8 pm = __builtin_elementwise_max(pp, pn);
      if (ev < 0) pm = SIX8;
      pmj[jj] = pm;
    }
#pragma unroll
    for (int h = 0; h < 8; ++h) {
      half2v wv = {pmj[0][h], pmj[1][h]};
      *(half2v*)&PA[cur][h][i_loc][2 * m] = wv;
    }

    // write next tile's staged s2 tables (loads have had phase A to land)
    if (jt < 7) {
      *(u16x8*)&s2t[cur ^ 1][t * 8]        = stA;
      *(u16x8*)&s2t[cur ^ 1][4096 + t * 8] = stB;
    }
    __syncthreads();

    // ---- Phase B: afrag from PA, numerator + denominator MFMAs
    half8 af0 = *(const half8*)&PA[cur][w][li][q * 8];
    half8 af1 = *(const half8*)&PA[cur][w][li][32 + q * 8];
    __builtin_amdgcn_s_setprio(1);
#pragma unroll
    for (int n = 0; n < 4; ++n) {
      acc[n] = __builtin_amdgcn_mfma_f32_16x16x32_f16(af0, bfrag[n][0], acc[n], 0, 0, 0);
      acc[n] = __builtin_amdgcn_mfma_f32_16x16x32_f16(af1, bfrag[n][1], acc[n], 0, 0, 0);
    }
    acc_l = __builtin_amdgcn_mfma_f32_16x16x32_f16(af0, ONE8, acc_l, 0, 0, 0);
    acc_l = __builtin_amdgcn_mfma_f32_16x16x32_f16(af1, ONE8, acc_l, 0, 0, 0);
    __builtin_amdgcn_s_setprio(0);

    eCur = eNxt;
    cur ^= 1;
  }

  // denominator rows: D[row=q*4+r][*] all-equal row sums
  if (li == 0) {
#pragma unroll
    for (int r = 0; r < 4; ++r)
      LPART[((size_t)ch * NN + i0 + q * 4 + r) * 8 + w] = acc_l[r];
  }

  // partial numerators. C layout: col = lane&15, row = (lane>>4)*4 + reg
  float* base = PART + (size_t)ch * NN * DD;
#pragma unroll
  for (int n = 0; n < 4; ++n) {
#pragma unroll
    for (int r = 0; r < 4; ++r) {
      int row = i0 + q * 4 + r;
      int col = w * 64 + n * 16 + li;
      base[(size_t)row * DD + col] = acc[n][r];
    }
  }
}

// ---------------------------------------------------------------------------
// Kernel 4: combine 4 j-chunk partials, divide by denominator, project.
// (scales cancel: num and denom both carry the 1/16) grid 512, block 256.
// ---------------------------------------------------------------------------
__global__ __launch_bounds__(256) void proj_kernel(
    const float* __restrict__ PART, const float* __restrict__ LPART,
    const float* __restrict__ Pw, const float* __restrict__ Pb,
    float* __restrict__ out) {
  __shared__ __align__(16) float preS[4][512];
  __shared__ float linv[4][8];
  int t = threadIdx.x;
  int r0 = blockIdx.x * 4;
  if (t < 32) {
    int i = t >> 3, h = t & 7;
    float s = 0.f;
#pragma unroll
    for (int c = 0; c < 4; ++c)
      s += LPART[(size_t)c * NN * 8 + (size_t)(r0 + i) * 8 + h];
    linv[i][h] = 1.0f / s;
  }
  __syncthreads();
  for (int idx = t; idx < 4 * 128; idx += 256) {
    int i = idx >> 7, hd = (idx & 127) * 4;
    float4 v = {0.f, 0.f, 0.f, 0.f};
#pragma unroll
    for (int c = 0; c < 4; ++c) {
      float4 p = *(const float4*)&PART[(size_t)c * NN * DD + (size_t)(r0 + i) * DD + hd];
      v.x += p.x; v.y += p.y; v.z += p.z; v.w += p.w;
    }
    float li2 = linv[i][hd >> 6];
    v.x *= li2; v.y *= li2; v.z *= li2; v.w *= li2;
    *(float4*)&preS[i][hd] = v;
  }
  __syncthreads();
  int c = t & 63, rq = t >> 6;
  float acc0 = Pb[c];
  for (int hq = 0; hq < 128; ++hq) {
    int hd = hq * 4;
    float4 p0 = *(const float4*)&preS[rq][hd];
    float w0 = Pw[(hd + 0) * 64 + c];
    float w1 = Pw[(hd + 1) * 64 + c];
    float w2 = Pw[(hd + 2) * 64 + c];
    float w3 = Pw[(hd + 3) * 64 + c];
    acc0 += p0.x * w0 + p0.y * w1 + p0.z * w2 + p0.w * w3;
  }
  out[(size_t)(r0 + rq) * 64 + c] = acc0;
}

// ---------------------------------------------------------------------------
extern "C" void kernel_launch(void* const* d_in, const int* in_sizes, int n_in,
                              void* d_out, int out_size, void* d_ws, size_t ws_size,
                              hipStream_t stream) {
  const float* X  = (const float*)d_in[0];
  const int*   E  = (const int*)d_in[1];
  const float* Qw = (const float*)d_in[2];
  const float* Qb = (const float*)d_in[3];
  const float* Kw = (const float*)d_in[4];
  const float* Kb = (const float*)d_in[5];
  const float* Vw = (const float*)d_in[6];
  const float* Vb = (const float*)d_in[7];
  const float* A  = (const float*)d_in[8];
  const float* Pw = (const float*)d_in[9];
  const float* Pb = (const float*)d_in[10];
  float* out = (float*)d_out;

  float* ws = (float*)d_ws;
  const size_t ND = (size_t)NN * DD;            // 1M floats
  float* Q     = ws;                            // [0, 1M)
  float* K     = ws + ND;                       // [1M, 2M)
  float* PART  = ws;                            // [0, 4M) (aliases Q/K, dead)
  u16*   TS1   = (u16*)(ws + 4 * ND);           // 512 KB
  u16*   TS2   = TS1 + (size_t)NN * 128;        // 512 KB
  u16*   VtH   = TS2 + (size_t)NN * 128;        // 2 MB
  float* LPART = (float*)(VtH + (size_t)DD * NN); // 256 KB

  qkv_kernel<<<384, 256, 0, stream>>>(X, Qw, Qb, Kw, Kb, Vw, Vb, Q, K, VtH);
  s12_kernel<<<512, 256, 0, stream>>>(Q, K, A, TS1, TS2);
  attn_mfma_kernel<<<512, 512, 0, stream>>>(E, TS1, TS2, VtH, PART, LPART);
  proj_kernel<<<512, 256, 0, stream>>>(PART, LPART, Pw, Pb, out);
}